// Round 1
// baseline (438.019 us; speedup 1.0000x reference)
//
#include <hip/hip_runtime.h>
#include <hip/hip_bf16.h>

// Problem constants (from reference)
#define M_TOTAL 65536   // N_IDS
#define NQ      2000
#define ND      128     // N_DOCS
#define FDIM    220     // FEATURE_DIM
#define KPAD    224     // FDIM padded to multiple of 32 for MFMA
#define HID     768     // HIDDEN
#define CHUNKS  56      // 55 data float4-chunks per row + 1 pad chunk

using bf16_t = __hip_bfloat16;
using bf16x8 = __attribute__((ext_vector_type(8))) short;  // 8 bf16 = 4 VGPRs
using f32x4  = __attribute__((ext_vector_type(4))) float;  // MFMA acc

struct __align__(8) bf4 { bf16_t a, b, c, d; };

__device__ __forceinline__ float slog(float x) {
  // log(|x|+1) * sign(x)
  return copysignf(log1pf(fabsf(x)), x);
}

// ---------------------------------------------------------------------------
// Kernel 1: gather rows of feature_table by (qid,did), apply signed log1p,
// write fp32 feature_batch (output 2) and bf16 K-padded copy for the GEMM.
// ---------------------------------------------------------------------------
__global__ __launch_bounds__(256) void gather_transform_kernel(
    const int* __restrict__ ids, const float* __restrict__ table,
    float* __restrict__ fb_f32, bf16_t* __restrict__ fbB)
{
  int i   = blockIdx.x * 256 + threadIdx.x;
  int row = i / CHUNKS;
  int c4  = i % CHUNKS;
  if (row >= M_TOTAL) return;

  if (c4 == 55) {  // zero the 4 pad columns (ws is poisoned 0xAA)
    bf4 z; z.a = __float2bfloat16(0.f); z.b = z.a; z.c = z.a; z.d = z.a;
    *(bf4*)(fbB + (size_t)row * KPAD + FDIM) = z;
    return;
  }

  int qid = ids[2 * row];
  int did = ids[2 * row + 1];
  const float4 x =
      *(const float4*)(table + ((size_t)qid * ND + did) * FDIM + c4 * 4);
  float4 y;
  y.x = slog(x.x); y.y = slog(x.y); y.z = slog(x.z); y.w = slog(x.w);
  *(float4*)(fb_f32 + (size_t)row * FDIM + c4 * 4) = y;

  bf4 h;
  h.a = __float2bfloat16(y.x); h.b = __float2bfloat16(y.y);
  h.c = __float2bfloat16(y.z); h.d = __float2bfloat16(y.w);
  *(bf4*)(fbB + (size_t)row * KPAD + c4 * 4) = h;
}

// ---------------------------------------------------------------------------
// Kernel 2: convert W (768x220 fp32) to bf16, K-padded to 224.
// ---------------------------------------------------------------------------
__global__ __launch_bounds__(256) void convert_w_kernel(
    const float* __restrict__ W, bf16_t* __restrict__ Wb)
{
  int i   = blockIdx.x * 256 + threadIdx.x;
  int row = i / CHUNKS;
  int c4  = i % CHUNKS;
  if (row >= HID) return;

  if (c4 == 55) {
    bf4 z; z.a = __float2bfloat16(0.f); z.b = z.a; z.c = z.a; z.d = z.a;
    *(bf4*)(Wb + (size_t)row * KPAD + FDIM) = z;
    return;
  }
  const float4 x = *(const float4*)(W + (size_t)row * FDIM + c4 * 4);
  bf4 h;
  h.a = __float2bfloat16(x.x); h.b = __float2bfloat16(x.y);
  h.c = __float2bfloat16(x.z); h.d = __float2bfloat16(x.w);
  *(bf4*)(Wb + (size_t)row * KPAD + c4 * 4) = h;
}

// ---------------------------------------------------------------------------
// Kernel 3: out = relu(A @ B^T + bias), A=[M,224] bf16, B=[768,224] bf16,
// out=[M,768] fp32. m97 structure: 128x128 tile, 4 waves, each wave 64x64
// (4x4 frags of 16x16x32), global_load_lds width=16 staging, BK=32.
// ---------------------------------------------------------------------------
__global__ __launch_bounds__(256, 2) void gemm_bias_relu_kernel(
    const bf16_t* __restrict__ A, const bf16_t* __restrict__ B,
    const float* __restrict__ bias, float* __restrict__ out)
{
  __shared__ bf16_t As[128 * 32];
  __shared__ bf16_t Bs[128 * 32];

  const int tid  = threadIdx.x;
  const int wave = tid >> 6;
  const int lane = tid & 63;
  const int bn   = blockIdx.x;  // 0..5   (N tiles, fastest -> A-tile reuse in L2)
  const int bm   = blockIdx.y;  // 0..511 (M tiles)
  const int wm   = wave & 1;
  const int wn   = wave >> 1;
  const int l15  = lane & 15;
  const int q    = lane >> 4;

  f32x4 acc[4][4];
#pragma unroll
  for (int i = 0; i < 4; ++i)
#pragma unroll
    for (int j = 0; j < 4; ++j) acc[i][j] = (f32x4){0.f, 0.f, 0.f, 0.f};

  const size_t arow0 = (size_t)bm * 128;
  const size_t brow0 = (size_t)bn * 128;

  for (int k0 = 0; k0 < KPAD; k0 += 32) {
    // Stage A/B tiles: 128 rows x 32 cols bf16 = 8 KB = 512 chunks of 16 B.
    // LDS dest is wave-uniform base + lane*16 (hardware rule), so LDS layout
    // is exactly row-major [128][32] with chunk ch -> row=ch/4, col8=(ch%4)*8.
#pragma unroll
    for (int j = 0; j < 2; ++j) {
      const int chbase = j * 256 + wave * 64;
      const int ch     = chbase + lane;
      const int r      = ch >> 2;
      const int cc     = (ch & 3) * 8;
      __builtin_amdgcn_global_load_lds(
          (const __attribute__((address_space(1))) void*)(A + (arow0 + r) * KPAD + k0 + cc),
          (__attribute__((address_space(3))) void*)(As + chbase * 8), 16, 0, 0);
      __builtin_amdgcn_global_load_lds(
          (const __attribute__((address_space(1))) void*)(B + (brow0 + r) * KPAD + k0 + cc),
          (__attribute__((address_space(3))) void*)(Bs + chbase * 8), 16, 0, 0);
    }
    __syncthreads();  // compiler drains vmcnt(0) before s_barrier

    bf16x8 af[4], bg[4];
#pragma unroll
    for (int mi = 0; mi < 4; ++mi)
      af[mi] = *(const bf16x8*)(As + (wm * 64 + mi * 16 + l15) * 32 + q * 8);
#pragma unroll
    for (int ni = 0; ni < 4; ++ni)
      bg[ni] = *(const bf16x8*)(Bs + (wn * 64 + ni * 16 + l15) * 32 + q * 8);

#pragma unroll
    for (int mi = 0; mi < 4; ++mi)
#pragma unroll
      for (int ni = 0; ni < 4; ++ni)
        acc[mi][ni] = __builtin_amdgcn_mfma_f32_16x16x32_bf16(
            af[mi], bg[ni], acc[mi][ni], 0, 0, 0);

    __syncthreads();  // protect LDS from next iteration's staging
  }

  // Epilogue: C/D layout col = lane&15, row = (lane>>4)*4 + reg  [m89-verified]
  const int col0 = bn * 128 + wn * 64 + l15;
  const int row0 = bm * 128 + wm * 64 + q * 4;
#pragma unroll
  for (int ni = 0; ni < 4; ++ni) {
    const int n    = col0 + ni * 16;
    const float bv = bias[n];
#pragma unroll
    for (int mi = 0; mi < 4; ++mi) {
#pragma unroll
      for (int r = 0; r < 4; ++r) {
        float v = acc[mi][ni][r] + bv;
        out[(size_t)(row0 + mi * 16 + r) * HID + n] = v > 0.f ? v : 0.f;
      }
    }
  }
}

extern "C" void kernel_launch(void* const* d_in, const int* in_sizes, int n_in,
                              void* d_out, int out_size, void* d_ws, size_t ws_size,
                              hipStream_t stream) {
  (void)in_sizes; (void)n_in; (void)out_size; (void)ws_size;

  const int*   ids   = (const int*)d_in[0];
  const float* table = (const float*)d_in[1];
  const float* W     = (const float*)d_in[2];
  const float* bias  = (const float*)d_in[3];

  float* out_embeds = (float*)d_out;                          // 65536*768 fp32
  float* fb_f32     = (float*)d_out + (size_t)M_TOTAL * HID;  // 65536*220 fp32

  bf16_t* fbB = (bf16_t*)d_ws;                      // 65536*224 bf16 (29.4 MB)
  bf16_t* Wb  = fbB + (size_t)M_TOTAL * KPAD;       // 768*224 bf16

  gather_transform_kernel<<<(M_TOTAL * CHUNKS) / 256, 256, 0, stream>>>(
      ids, table, fb_f32, fbB);
  convert_w_kernel<<<(HID * CHUNKS) / 256, 256, 0, stream>>>(W, Wb);

  dim3 grid(HID / 128, M_TOTAL / 128);  // (6, 512), bn fastest for A reuse
  gemm_bias_relu_kernel<<<grid, 256, 0, stream>>>(fbB, Wb, bias, out_embeds);
}

// Round 2
// 437.966 us; speedup vs baseline: 1.0001x; 1.0001x over previous
//
#include <hip/hip_runtime.h>
#include <hip/hip_bf16.h>

// Problem constants (from reference)
#define M_TOTAL 65536   // N_IDS
#define ND      128     // N_DOCS
#define FDIM    220     // FEATURE_DIM
#define KPAD    224     // FDIM padded to multiple of 32 for MFMA
#define HID     768     // HIDDEN
#define CHUNKS  56      // 55 data float4-chunks per row + 1 pad chunk
#define BSTRIDE 232     // LDS row stride (bf16 elems) for B tile:
                        // 464 B rows -> 16B-aligned, 2-way bank conflict (free per m136)

using bf16_t = __hip_bfloat16;
using bf16x8 = __attribute__((ext_vector_type(8))) short;  // 8 bf16 = 4 VGPRs
using f32x4  = __attribute__((ext_vector_type(4))) float;  // MFMA acc

struct __align__(8)  bf4    { bf16_t a, b, c, d; };
struct __align__(16) bf16v8 { bf16_t v[8]; };

__device__ __forceinline__ float slog(float x) {
  return copysignf(log1pf(fabsf(x)), x);  // log(|x|+1) * sign(x)
}

// ---------------------------------------------------------------------------
// Kernel 1: gather rows of feature_table by (qid,did), apply signed log1p,
// write fp32 feature_batch (output 2) and bf16 K-padded copy for the GEMM.
// ---------------------------------------------------------------------------
__global__ __launch_bounds__(256) void gather_transform_kernel(
    const int* __restrict__ ids, const float* __restrict__ table,
    float* __restrict__ fb_f32, bf16_t* __restrict__ fbB)
{
  int i   = blockIdx.x * 256 + threadIdx.x;
  int row = i / CHUNKS;
  int c4  = i % CHUNKS;
  if (row >= M_TOTAL) return;

  if (c4 == 55) {  // zero the 4 pad columns (ws is poisoned 0xAA)
    bf4 z; z.a = __float2bfloat16(0.f); z.b = z.a; z.c = z.a; z.d = z.a;
    *(bf4*)(fbB + (size_t)row * KPAD + FDIM) = z;
    return;
  }

  int qid = ids[2 * row];
  int did = ids[2 * row + 1];
  const float4 x =
      *(const float4*)(table + ((size_t)qid * ND + did) * FDIM + c4 * 4);
  float4 y;
  y.x = slog(x.x); y.y = slog(x.y); y.z = slog(x.z); y.w = slog(x.w);
  *(float4*)(fb_f32 + (size_t)row * FDIM + c4 * 4) = y;

  bf4 h;
  h.a = __float2bfloat16(y.x); h.b = __float2bfloat16(y.y);
  h.c = __float2bfloat16(y.z); h.d = __float2bfloat16(y.w);
  *(bf4*)(fbB + (size_t)row * KPAD + c4 * 4) = h;
}

// ---------------------------------------------------------------------------
// Kernel 2: out = relu(A @ W^T + bias), A=[M,224] bf16 (ws), W=[768,220] fp32.
// Block = 128 rows x 128 cols x FULL K=224. W tile staged ONCE into LDS
// (fp32->bf16 inline, padded stride 232). K-loop is barrier-free: A fragments
// come straight from global (wave reads 16 rows x 64B contiguous — L3-resident
// 29 MB working set), B fragments from LDS. 7 unrolled K-steps, 112 MFMA/wave
// with 16 independent acc chains.
// ---------------------------------------------------------------------------
__global__ __launch_bounds__(256, 2) void gemm_bias_relu_kernel(
    const bf16_t* __restrict__ A, const float* __restrict__ W,
    const float* __restrict__ bias, float* __restrict__ out)
{
  __shared__ bf16_t Bs[128 * BSTRIDE];  // 59392 B -> 2 blocks/CU

  const int tid = threadIdx.x;
  const int bn  = blockIdx.x;  // 0..5   (N tiles, fastest -> A-tile temporal reuse)
  const int bm  = blockIdx.y;  // 0..511 (M tiles)

  // ---- stage W tile: 128 rows x 224 cols (fp32 -> bf16), one time ----
  // 128 rows x 28 groups-of-8-cols = 3584 groups; 256 threads x 14 iters.
#pragma unroll
  for (int it = 0; it < 14; ++it) {
    const int j   = it * 256 + tid;
    const int row = j / 28;
    const int g   = j % 28;
    const float* src = W + (size_t)(bn * 128 + row) * FDIM + g * 8;
    const float4 f0 = *(const float4*)src;          // cols g*8 .. g*8+3 (<220 ok)
    float4 f1;
    if (g < 27) {
      f1 = *(const float4*)(src + 4);               // cols g*8+4 .. g*8+7
    } else {
      f1.x = 0.f; f1.y = 0.f; f1.z = 0.f; f1.w = 0.f;  // cols 220..223 pad = 0
    }
    bf16v8 h;
    h.v[0] = __float2bfloat16(f0.x); h.v[1] = __float2bfloat16(f0.y);
    h.v[2] = __float2bfloat16(f0.z); h.v[3] = __float2bfloat16(f0.w);
    h.v[4] = __float2bfloat16(f1.x); h.v[5] = __float2bfloat16(f1.y);
    h.v[6] = __float2bfloat16(f1.z); h.v[7] = __float2bfloat16(f1.w);
    *(bf16v8*)(Bs + row * BSTRIDE + g * 8) = h;
  }
  __syncthreads();  // the ONLY barrier

  const int wave = tid >> 6;
  const int lane = tid & 63;
  const int wm   = wave & 1;
  const int wn   = wave >> 1;
  const int l15  = lane & 15;
  const int q    = lane >> 4;

  f32x4 acc[4][4];
#pragma unroll
  for (int i = 0; i < 4; ++i)
#pragma unroll
    for (int j = 0; j < 4; ++j) acc[i][j] = (f32x4){0.f, 0.f, 0.f, 0.f};

  // A fragment base: row = bm*128 + wm*64 + mi*16 + l15, k = kb*32 + q*8
  const bf16_t* Abase  = A + (size_t)(bm * 128 + wm * 64 + l15) * KPAD + q * 8;
  const bf16_t* BsBase = Bs + (wn * 64 + l15) * BSTRIDE + q * 8;

#pragma unroll
  for (int kb = 0; kb < 7; ++kb) {
    bf16x8 af[4], bg[4];
#pragma unroll
    for (int mi = 0; mi < 4; ++mi)
      af[mi] = *(const bf16x8*)(Abase + (size_t)mi * 16 * KPAD + kb * 32);
#pragma unroll
    for (int ni = 0; ni < 4; ++ni)
      bg[ni] = *(const bf16x8*)(BsBase + ni * 16 * BSTRIDE + kb * 32);
#pragma unroll
    for (int mi = 0; mi < 4; ++mi)
#pragma unroll
      for (int ni = 0; ni < 4; ++ni)
        acc[mi][ni] = __builtin_amdgcn_mfma_f32_16x16x32_bf16(
            af[mi], bg[ni], acc[mi][ni], 0, 0, 0);
  }

  // Epilogue: C/D layout col = lane&15, row = (lane>>4)*4 + reg  [m89-verified]
  const int col0 = bn * 128 + wn * 64 + l15;
  const int row0 = bm * 128 + wm * 64 + q * 4;
#pragma unroll
  for (int ni = 0; ni < 4; ++ni) {
    const int n    = col0 + ni * 16;
    const float bv = bias[n];
#pragma unroll
    for (int mi = 0; mi < 4; ++mi) {
#pragma unroll
      for (int r = 0; r < 4; ++r) {
        float v = acc[mi][ni][r] + bv;
        out[(size_t)(row0 + mi * 16 + r) * HID + n] = v > 0.f ? v : 0.f;
      }
    }
  }
}

extern "C" void kernel_launch(void* const* d_in, const int* in_sizes, int n_in,
                              void* d_out, int out_size, void* d_ws, size_t ws_size,
                              hipStream_t stream) {
  (void)in_sizes; (void)n_in; (void)out_size; (void)ws_size;

  const int*   ids   = (const int*)d_in[0];
  const float* table = (const float*)d_in[1];
  const float* W     = (const float*)d_in[2];
  const float* bias  = (const float*)d_in[3];

  float* out_embeds = (float*)d_out;                          // 65536*768 fp32
  float* fb_f32     = (float*)d_out + (size_t)M_TOTAL * HID;  // 65536*220 fp32

  bf16_t* fbB = (bf16_t*)d_ws;  // 65536*224 bf16 (29.4 MB)

  gather_transform_kernel<<<(M_TOTAL * CHUNKS) / 256, 256, 0, stream>>>(
      ids, table, fb_f32, fbB);

  dim3 grid(HID / 128, M_TOTAL / 128);  // (6, 512), bn fastest for A reuse
  gemm_bias_relu_kernel<<<grid, 256, 0, stream>>>(fbB, W, bias, out_embeds);
}